// Round 1
// baseline (83.378 us; speedup 1.0000x reference)
//
#include <hip/hip_runtime.h>
#include <math.h>

// out[b,c] = tanh( sum_{hw} x[b,c,h,w] * W[c,h,w] + bias[c] )
// x: [B, C, 7, 7] f32 contiguous -> each (b,c) "row" = 49 contiguous floats.
// Memory-bound: stage 256 rows (50176 B, 16B-aligned chunk) per 256-thread
// block into LDS with coalesced float4 loads; each thread reduces one row.

constexpr int K    = 49;   // 7*7
constexpr int ROWS = 256;  // rows per block == threads per block

__global__ __launch_bounds__(256) void WGP_84018150245011_kernel(
    const float* __restrict__ x,
    const float* __restrict__ W,
    const float* __restrict__ bias,
    float* __restrict__ out,
    int C) {
  __shared__ float xs[ROWS * K];  // 50176 B; stride-49 reads -> 2-way bank alias (free)

  const int tid = threadIdx.x;

  // ---- Stage: 256 rows = 3136 float4, block-contiguous & 16B aligned ----
  const float4* __restrict__ src4 =
      reinterpret_cast<const float4*>(x) + (size_t)blockIdx.x * (ROWS * K / 4);
  float4* dst4 = reinterpret_cast<float4*>(xs);
#pragma unroll
  for (int j = 0; j < 12; ++j) {          // 12*256 = 3072 float4
    dst4[tid + j * 256] = src4[tid + j * 256];
  }
  if (tid < 64) {                         // remaining 64 float4
    dst4[tid + 3072] = src4[tid + 3072];
  }
  __syncthreads();

  // ---- Reduce: thread t owns row t of this block's tile ----
  const size_t row = (size_t)blockIdx.x * ROWS + tid;
  const int c = (int)(row % (size_t)C);
  const float* __restrict__ wr = W + (size_t)c * K;   // L2-resident, 4096x reuse
  const float* xr = xs + tid * K;

  float s = bias[c];
#pragma unroll
  for (int k = 0; k < K; ++k) {
    s = fmaf(xr[k], wr[k], s);
  }
  out[row] = tanhf(s);
}

extern "C" void kernel_launch(void* const* d_in, const int* in_sizes, int n_in,
                              void* d_out, int out_size, void* d_ws, size_t ws_size,
                              hipStream_t stream) {
  const float* x    = (const float*)d_in[0];
  const float* W    = (const float*)d_in[1];
  const float* bias = (const float*)d_in[2];
  float* out        = (float*)d_out;

  const int C      = in_sizes[2];            // 512
  const int n_rows = in_sizes[0] / K;        // B*C = 2,097,152
  const int grid   = n_rows / ROWS;          // 8192 (exact)

  WGP_84018150245011_kernel<<<grid, ROWS, 0, stream>>>(x, W, bias, out, C);
}

// Round 2
// 83.355 us; speedup vs baseline: 1.0003x; 1.0003x over previous
//
#include <hip/hip_runtime.h>
#include <math.h>

// out[b,c] = tanh( sum_{hw} x[b,c,h,w] * W[c,h,w] + bias[c] )
// x: [B=4096, C=512, 7, 7] f32. Each (b,c) row = 49 contiguous floats.
// Memory-bound streaming kernel:
//  - 256-row tiles (50176 B) staged to LDS with coalesced float4 loads
//  - grid-stride over tiles with even grid => each thread's channel c is
//    loop-invariant => W row (49 floats) + bias hoisted into registers ONCE
//    (kills the lane-strided per-tile W gather that cost ~20 us in R1)

constexpr int K    = 49;   // 7*7
constexpr int ROWS = 256;  // rows per tile == threads per block
constexpr int GRID = 2048; // EVEN => tile parity (g%2) constant per block

__global__ __launch_bounds__(256) void WGP_84018150245011_kernel(
    const float* __restrict__ x,
    const float* __restrict__ W,
    const float* __restrict__ bias,
    float* __restrict__ out,
    int n_tiles) {
  __shared__ float xs[ROWS * K];  // 50176 B; stride-49 reads -> bank stride 17, conflict-free

  const int tid = threadIdx.x;

  // Channel for this thread is the same for every tile this block touches:
  // tile g covers rows [256g, 256g+256), row = 256g + tid, c = row % 512
  //   = (g%2)*256 + tid, and g%2 == blockIdx.x%2 since GRID is even.
  const int c = ((blockIdx.x & 1) << 8) | tid;

  // Hoist W row + bias into registers (loop-invariant).
  float w[K];
  const float* __restrict__ wr = W + c * K;
#pragma unroll
  for (int k = 0; k < K; ++k) w[k] = wr[k];
  const float bi = bias[c];

  for (int g = blockIdx.x; g < n_tiles; g += GRID) {
    // ---- Stage: 3136 float4, block-contiguous & 16B aligned ----
    const float4* __restrict__ src4 =
        reinterpret_cast<const float4*>(x) + (size_t)g * (ROWS * K / 4);
    float4* dst4 = reinterpret_cast<float4*>(xs);
#pragma unroll
    for (int j = 0; j < 12; ++j) {          // 12*256 = 3072 float4
      dst4[tid + j * 256] = src4[tid + j * 256];
    }
    if (tid < 64) {                         // remaining 64 float4
      dst4[tid + 3072] = src4[tid + 3072];
    }
    __syncthreads();

    // ---- Reduce: thread t owns row t of this tile ----
    const float* xr = xs + tid * K;
    float s = bi;
#pragma unroll
    for (int k = 0; k < K; ++k) {
      s = fmaf(xr[k], w[k], s);
    }
    out[(size_t)g * ROWS + tid] = tanhf(s);
    __syncthreads();  // WAR guard before next tile's stage
  }
}

extern "C" void kernel_launch(void* const* d_in, const int* in_sizes, int n_in,
                              void* d_out, int out_size, void* d_ws, size_t ws_size,
                              hipStream_t stream) {
  const float* x    = (const float*)d_in[0];
  const float* W    = (const float*)d_in[1];
  const float* bias = (const float*)d_in[2];
  float* out        = (float*)d_out;

  const int n_rows  = in_sizes[0] / K;       // B*C = 2,097,152
  const int n_tiles = n_rows / ROWS;         // 8192 (exact)

  WGP_84018150245011_kernel<<<GRID, ROWS, 0, stream>>>(x, W, bias, out, n_tiles);
}